// Round 10
// baseline (450.754 us; speedup 1.0000x reference)
//
#include <hip/hip_runtime.h>

#define NN 50000
#define NE 800000
#define SCAN_NB ((NN + 255) / 256)

typedef short bf16x8 __attribute__((ext_vector_type(8)));
typedef float f32x4 __attribute__((ext_vector_type(4)));

// ------------------------------------------------ bf16 helpers (ushort = bf16)
__device__ inline void bf16x8_to_f32(const uint4 v, float* f) {
    f[0] = __uint_as_float(v.x << 16);
    f[1] = __uint_as_float(v.x & 0xffff0000u);
    f[2] = __uint_as_float(v.y << 16);
    f[3] = __uint_as_float(v.y & 0xffff0000u);
    f[4] = __uint_as_float(v.z << 16);
    f[5] = __uint_as_float(v.z & 0xffff0000u);
    f[6] = __uint_as_float(v.w << 16);
    f[7] = __uint_as_float(v.w & 0xffff0000u);
}

__device__ inline unsigned f32_to_bf16(float x) {  // RTNE
    unsigned u = __float_as_uint(x);
    return (u + 0x7fffu + ((u >> 16) & 1u)) >> 16;
}

__device__ inline uint4 f32x8_to_bf16(const float* f) {
    uint4 v;
    v.x = f32_to_bf16(f[0]) | (f32_to_bf16(f[1]) << 16);
    v.y = f32_to_bf16(f[2]) | (f32_to_bf16(f[3]) << 16);
    v.z = f32_to_bf16(f[4]) | (f32_to_bf16(f[5]) << 16);
    v.w = f32_to_bf16(f[6]) | (f32_to_bf16(f[7]) << 16);
    return v;
}

// ------------------------------------------------ hist + per-edge rank
__global__ __launch_bounds__(256) void hist_rank_kernel(const int* __restrict__ dst,
                                                        int* __restrict__ cnt,
                                                        int* __restrict__ rank) {
    int i = blockIdx.x * blockDim.x + threadIdx.x;
    if (i < NE) rank[i] = atomicAdd(&cnt[dst[i]], 1);
}

// ------------------------------------------------ 3-kernel parallel scan
__global__ __launch_bounds__(256) void scan_block_kernel(const int* __restrict__ cnt,
                                                         int* __restrict__ row_ptr,
                                                         int* __restrict__ partial,
                                                         int n) {
    __shared__ int wsums[4];
    int i = blockIdx.x * 256 + threadIdx.x;
    int v = (i < n) ? cnt[i] : 0;
    const int lane = threadIdx.x & 63;
    const int wid = threadIdx.x >> 6;
    int incl = v;
    #pragma unroll
    for (int off = 1; off < 64; off <<= 1) {
        int t = __shfl_up(incl, off);
        if (lane >= off) incl += t;
    }
    if (lane == 63) wsums[wid] = incl;
    __syncthreads();
    int woff = 0;
    #pragma unroll
    for (int w = 0; w < 4; ++w)
        if (w < wid) woff += wsums[w];
    if (i < n) row_ptr[i] = woff + incl - v;
    if (threadIdx.x == 0)
        partial[blockIdx.x] = wsums[0] + wsums[1] + wsums[2] + wsums[3];
}

__global__ __launch_bounds__(256) void scan_partials_kernel(int* __restrict__ partial,
                                                            int* __restrict__ pexcl,
                                                            int* __restrict__ row_ptr,
                                                            int np) {
    __shared__ int wsums[4];
    int v = (threadIdx.x < np) ? partial[threadIdx.x] : 0;
    const int lane = threadIdx.x & 63;
    const int wid = threadIdx.x >> 6;
    int incl = v;
    #pragma unroll
    for (int off = 1; off < 64; off <<= 1) {
        int t = __shfl_up(incl, off);
        if (lane >= off) incl += t;
    }
    if (lane == 63) wsums[wid] = incl;
    __syncthreads();
    int woff = 0;
    #pragma unroll
    for (int w = 0; w < 4; ++w)
        if (w < wid) woff += wsums[w];
    if (threadIdx.x < np) pexcl[threadIdx.x] = woff + incl - v;
    if (threadIdx.x == 0) row_ptr[NN] = NE;
}

__global__ __launch_bounds__(256) void scan_add_kernel(int* __restrict__ row_ptr,
                                                       const int* __restrict__ pexcl,
                                                       int n) {
    int i = blockIdx.x * 256 + threadIdx.x;
    if (i < n) row_ptr[i] += pexcl[blockIdx.x];
}

// ------------------------------------------------ CSR fill (atomic-free, 4B rec)
__global__ __launch_bounds__(256) void fill_kernel(const int* __restrict__ src,
                                                   const int* __restrict__ dst,
                                                   const float* __restrict__ w,
                                                   const int* __restrict__ row_ptr,
                                                   const int* __restrict__ rank,
                                                   unsigned* __restrict__ er) {
    int i = blockIdx.x * blockDim.x + threadIdx.x;
    if (i < NE) {
        int p = row_ptr[dst[i]] + rank[i];
        er[p] = (f32_to_bf16(w[i]) << 16) | (unsigned)src[i];
    }
}

// ------------------------------------------------ weighted in-degree per node
__global__ __launch_bounds__(256) void degw_kernel(const int* __restrict__ row_ptr,
                                                   const unsigned* __restrict__ er,
                                                   float* __restrict__ degw) {
    int n = blockIdx.x * 256 + threadIdx.x;
    if (n < NN) {
        float s = 0.f;
        int end = row_ptr[n + 1];
        for (int e = row_ptr[n]; e < end; ++e)
            s += __uint_as_float(er[e] & 0xffff0000u);
        degw[n] = s;
    }
}

// ------------------------------------------------ W12T[n][k] = sum_j W1[k][j]*W2[j][n]
__global__ __launch_bounds__(256) void w12t_kernel(const float* __restrict__ W1,
                                                   const float* __restrict__ W2,
                                                   unsigned short* __restrict__ W12T) {
    int i = blockIdx.x * 256 + threadIdx.x;  // i = n*256 + k
    if (i < 64 * 256) {
        int n = i >> 8, k = i & 255;
        float s = 0.f;
        for (int j = 0; j < 128; ++j)
            s += W1[(size_t)k * 128 + j] * W2[(size_t)j * 64 + n];
        W12T[i] = (unsigned short)f32_to_bf16(s);
    }
}

// ------------------------------------------------ c[d] = sum_k b1[k]*W2[k][d]
__global__ __launch_bounds__(64) void cvec_kernel(const float* __restrict__ b1,
                                                  const float* __restrict__ W2,
                                                  float* __restrict__ c) {
    int d = threadIdx.x;
    float s = 0.f;
    for (int k = 0; k < 128; ++k) s += b1[k] * W2[(size_t)k * 64 + d];
    c[d] = s;
}

// ------------------------------------------------ MFMA bf16 GEMM (A fp32)
// Output written in SPLIT half-feature layout: cols 0..31 -> Clo, 32..63 -> Chi
template <int N, int K>
__global__ __launch_bounds__(256) void gemm_mfma_kernel(
    const float* __restrict__ A, const unsigned short* __restrict__ BT,
    unsigned short* __restrict__ Clo, unsigned short* __restrict__ Chi, int M) {
    constexpr int NT = N / 16;
    constexpr int KS = K / 32;
    __shared__ unsigned short As[64][40];
    __shared__ unsigned short Bs[N][40];

    const int tid = threadIdx.x;
    const int wave = tid >> 6;
    const int lane = tid & 63;
    const int lm = lane & 15;
    const int lq = lane >> 4;
    const int row0 = blockIdx.x * 64;
    const int m0 = wave * 16;

    f32x4 acc[NT] = {};

    for (int ks = 0; ks < KS; ++ks) {
        const int k0 = ks * 32;
        {
            int m = tid >> 2, kc = (tid & 3) * 8;
            int gm = row0 + m;
            if (gm >= M) gm = M - 1;
            float4 v0 = *(const float4*)(A + (size_t)gm * K + k0 + kc);
            float4 v1 = *(const float4*)(A + (size_t)gm * K + k0 + kc + 4);
            float f[8] = {v0.x, v0.y, v0.z, v0.w, v1.x, v1.y, v1.z, v1.w};
            *(uint4*)&As[m][kc] = f32x8_to_bf16(f);
        }
        #pragma unroll
        for (int c = tid; c < N * 4; c += 256) {
            int n = c >> 2, kc = (c & 3) * 8;
            *(uint4*)&Bs[n][kc] = *(const uint4*)(BT + (size_t)n * K + k0 + kc);
        }
        __syncthreads();
        bf16x8 a = *(const bf16x8*)&As[m0 + lm][lq * 8];
        #pragma unroll
        for (int t = 0; t < NT; ++t) {
            bf16x8 b = *(const bf16x8*)&Bs[t * 16 + lm][lq * 8];
            acc[t] = __builtin_amdgcn_mfma_f32_16x16x32_bf16(a, b, acc[t], 0, 0, 0);
        }
        __syncthreads();
    }
    #pragma unroll
    for (int t = 0; t < NT; ++t) {
        #pragma unroll
        for (int r = 0; r < 4; ++r) {
            int gm = row0 + m0 + lq * 4 + r;
            if (gm < M) {
                int col = t * 16 + lm;
                unsigned short v = (unsigned short)f32_to_bf16(acc[t][r]);
                if (col < 32)
                    Clo[(size_t)gm * 32 + col] = v;
                else
                    Chi[(size_t)gm * 32 + col - 32] = v;
            }
        }
    }
}

// ------------------------------------------------ propagation, split half-features
// Two phases; phase p gathers only x_p (3.2 MB -> fits per-XCD L2).
// 64 nodes/block, 4 threads/node (16B each). rec = bf16(w)<<16 | src.
// MODE 0: out=acc   MODE 2: out=acc+degw*c+b2   MODE 1: out=0.9*acc+0.1*h
template <int MODE, bool OUT_BF16>
__global__ __launch_bounds__(256, 4) void prop_kernel(
    const int* __restrict__ row_ptr, const unsigned* __restrict__ er,
    const unsigned short* __restrict__ x_lo, const unsigned short* __restrict__ x_hi,
    const float* __restrict__ cvec, const float* __restrict__ b2,
    const float* __restrict__ degw,
    const unsigned short* __restrict__ h_lo, const unsigned short* __restrict__ h_hi,
    void* __restrict__ out_lo, void* __restrict__ out_hi) {
    const int local = threadIdx.x >> 2;   // 64 nodes/block
    const int lane = threadIdx.x & 3;     // 4 threads/node
    const int n = blockIdx.x * 64 + local;
    if (n >= NN) return;

    const int beg = row_ptr[n];
    const int cnt = row_ptr[n + 1] - beg;
    const unsigned* gr = er + beg;
    float dw = 0.f;
    if (MODE == 2) dw = degw[n];

    #pragma unroll
    for (int ph = 0; ph < 2; ++ph) {
        const unsigned short* x = ph ? x_hi : x_lo;
        float acc[8] = {};
        float f[8];
        #define ACCUM(rr, uu)                                       \
            {                                                       \
                float wv = __uint_as_float((rr) & 0xffff0000u);     \
                bf16x8_to_f32(uu, f);                               \
                _Pragma("unroll") for (int j = 0; j < 8; ++j)       \
                    acc[j] += wv * f[j];                            \
            }
        int i = 0;
        for (; i + 7 < cnt; i += 8) {
            unsigned r0 = gr[i + 0], r1 = gr[i + 1], r2 = gr[i + 2], r3 = gr[i + 3];
            unsigned r4 = gr[i + 4], r5 = gr[i + 5], r6 = gr[i + 6], r7 = gr[i + 7];
            uint4 u0 = *(const uint4*)(x + (size_t)(r0 & 0xffffu) * 32 + lane * 8);
            uint4 u1 = *(const uint4*)(x + (size_t)(r1 & 0xffffu) * 32 + lane * 8);
            uint4 u2 = *(const uint4*)(x + (size_t)(r2 & 0xffffu) * 32 + lane * 8);
            uint4 u3 = *(const uint4*)(x + (size_t)(r3 & 0xffffu) * 32 + lane * 8);
            uint4 u4 = *(const uint4*)(x + (size_t)(r4 & 0xffffu) * 32 + lane * 8);
            uint4 u5 = *(const uint4*)(x + (size_t)(r5 & 0xffffu) * 32 + lane * 8);
            uint4 u6 = *(const uint4*)(x + (size_t)(r6 & 0xffffu) * 32 + lane * 8);
            uint4 u7 = *(const uint4*)(x + (size_t)(r7 & 0xffffu) * 32 + lane * 8);
            ACCUM(r0, u0) ACCUM(r1, u1) ACCUM(r2, u2) ACCUM(r3, u3)
            ACCUM(r4, u4) ACCUM(r5, u5) ACCUM(r6, u6) ACCUM(r7, u7)
        }
        for (; i < cnt; ++i) {
            unsigned r0 = gr[i];
            uint4 u0 = *(const uint4*)(x + (size_t)(r0 & 0xffffu) * 32 + lane * 8);
            ACCUM(r0, u0)
        }
        #undef ACCUM

        float r[8];
        if (MODE == 0) {
            #pragma unroll
            for (int j = 0; j < 8; ++j) r[j] = acc[j];
        } else if (MODE == 2) {
            const int c0 = ph * 32 + lane * 8;
            #pragma unroll
            for (int j = 0; j < 8; ++j)
                r[j] = acc[j] + dw * cvec[c0 + j] + b2[c0 + j];
        } else {
            const unsigned short* h = ph ? h_hi : h_lo;
            uint4 uh = *(const uint4*)(h + (size_t)n * 32 + lane * 8);
            float fh[8];
            bf16x8_to_f32(uh, fh);
            #pragma unroll
            for (int j = 0; j < 8; ++j) r[j] = 0.9f * acc[j] + 0.1f * fh[j];
        }

        if (OUT_BF16) {
            unsigned short* o = (unsigned short*)(ph ? out_hi : out_lo);
            *(uint4*)(o + (size_t)n * 32 + lane * 8) = f32x8_to_bf16(r);
        } else {
            // fp32 full-width output: both pointers are d_out base
            float* o = (float*)out_lo + (size_t)n * 64 + ph * 32 + lane * 8;
            *(float4*)(o + 0) = make_float4(r[0], r[1], r[2], r[3]);
            *(float4*)(o + 4) = make_float4(r[4], r[5], r[6], r[7]);
        }
    }
}

__global__ void write_scalar_kernel(float* p, float v) { *p = v; }

// ------------------------------------------------ launch
extern "C" void kernel_launch(void* const* d_in, const int* in_sizes, int n_in,
                              void* d_out, int out_size, void* d_ws, size_t ws_size,
                              hipStream_t stream) {
    const float* features = (const float*)d_in[0];
    const int* edge_index = (const int*)d_in[1];
    const float* edge_w = (const float*)d_in[2];
    const float* W1 = (const float*)d_in[3];
    const float* b1 = (const float*)d_in[4];
    const float* W2 = (const float*)d_in[5];
    const float* b2 = (const float*)d_in[6];
    const int* src = edge_index;        // edge_index[0]
    const int* dst = edge_index + NE;   // edge_index[1]

    char* ws = (char*)d_ws;
    auto carve = [&](size_t bytes) {
        char* p = ws;
        ws += (bytes + 255) & ~(size_t)255;
        return p;
    };
    int* cnt = (int*)carve((size_t)NN * 4);
    int* rank = (int*)carve((size_t)NE * 4);
    int* row_ptr = (int*)carve((size_t)(NN + 1) * 4);
    int* partial = (int*)carve((size_t)SCAN_NB * 4);
    int* pexcl = (int*)carve((size_t)SCAN_NB * 4);
    unsigned* erec = (unsigned*)carve((size_t)NE * 4);
    float* degw = (float*)carve((size_t)NN * 4);
    float* cvec = (float*)carve((size_t)64 * 4);
    unsigned short* W12T = (unsigned short*)carve((size_t)64 * 256 * 2);
    const size_t HB = (size_t)NN * 32 * 2;   // one half-feature buffer
    unsigned short* z_lo = (unsigned short*)carve(HB);
    unsigned short* z_hi = (unsigned short*)carve(HB);
    unsigned short* p1_lo = (unsigned short*)carve(HB);
    unsigned short* p1_hi = (unsigned short*)carve(HB);
    unsigned short* h_lo = (unsigned short*)carve(HB);
    unsigned short* h_hi = (unsigned short*)carve(HB);
    unsigned short* a_lo = (unsigned short*)carve(HB);
    unsigned short* a_hi = (unsigned short*)carve(HB);
    unsigned short* b_lo = (unsigned short*)carve(HB);
    unsigned short* b_hi = (unsigned short*)carve(HB);

    const int EB = (NE + 255) / 256;
    const int PB = (NN + 63) / 64;   // prop blocks (64 nodes each)

    // ---- CSR build (by destination) ----
    hipMemsetAsync(cnt, 0, (size_t)NN * 4, stream);
    hist_rank_kernel<<<EB, 256, 0, stream>>>(dst, cnt, rank);
    scan_block_kernel<<<SCAN_NB, 256, 0, stream>>>(cnt, row_ptr, partial, NN);
    scan_partials_kernel<<<1, 256, 0, stream>>>(partial, pexcl, row_ptr, SCAN_NB);
    scan_add_kernel<<<SCAN_NB, 256, 0, stream>>>(row_ptr, pexcl, NN);
    fill_kernel<<<EB, 256, 0, stream>>>(src, dst, edge_w, row_ptr, rank, erec);
    degw_kernel<<<(NN + 255) / 256, 256, 0, stream>>>(row_ptr, erec, degw);

    // ---- fused weights: W12T = (W1@W2)^T bf16, cvec = b1@W2 ----
    w12t_kernel<<<64, 256, 0, stream>>>(W1, W2, W12T);
    cvec_kernel<<<1, 64, 0, stream>>>(b1, W2, cvec);

    // ---- z = F @ W12  [NN,64] bf16, split halves ----
    gemm_mfma_kernel<64, 256>
        <<<(NN + 63) / 64, 256, 0, stream>>>(features, W12T, z_lo, z_hi, NN);

    // ---- p1 = prop(z);  h = prop(p1) + degw*c + b2 ----
    prop_kernel<0, true><<<PB, 256, 0, stream>>>(
        row_ptr, erec, z_lo, z_hi, nullptr, nullptr, nullptr, nullptr, nullptr,
        p1_lo, p1_hi);
    prop_kernel<2, true><<<PB, 256, 0, stream>>>(
        row_ptr, erec, p1_lo, p1_hi, cvec, b2, degw, nullptr, nullptr,
        h_lo, h_hi);

    // ---- APPNP: 10 steps of x = 0.9*prop(x) + 0.1*h ----
    const unsigned short* xc_lo = h_lo;
    const unsigned short* xc_hi = h_hi;
    for (int k = 0; k < 9; ++k) {
        unsigned short* o_lo = (k & 1) ? b_lo : a_lo;
        unsigned short* o_hi = (k & 1) ? b_hi : a_hi;
        prop_kernel<1, true><<<PB, 256, 0, stream>>>(
            row_ptr, erec, xc_lo, xc_hi, nullptr, nullptr, nullptr, h_lo, h_hi,
            o_lo, o_hi);
        xc_lo = o_lo;
        xc_hi = o_hi;
    }
    prop_kernel<1, false><<<PB, 256, 0, stream>>>(
        row_ptr, erec, xc_lo, xc_hi, nullptr, nullptr, nullptr, h_lo, h_hi,
        d_out, d_out);

    // ---- second tuple element: the Python int 10 ----
    if (out_size > NN * 64) {
        write_scalar_kernel<<<1, 1, 0, stream>>>((float*)d_out + (size_t)NN * 64,
                                                 10.0f);
    }
}

// Round 12
// 364.488 us; speedup vs baseline: 1.2367x; 1.2367x over previous
//
#include <hip/hip_runtime.h>

#define NN 50000
#define NE 800000
#define SCAN_NB ((NN + 255) / 256)

typedef short bf16x8 __attribute__((ext_vector_type(8)));
typedef float f32x4 __attribute__((ext_vector_type(4)));

// ------------------------------------------------ bf16 helpers (ushort = bf16)
__device__ inline void bf16x8_to_f32(const uint4 v, float* f) {
    f[0] = __uint_as_float(v.x << 16);
    f[1] = __uint_as_float(v.x & 0xffff0000u);
    f[2] = __uint_as_float(v.y << 16);
    f[3] = __uint_as_float(v.y & 0xffff0000u);
    f[4] = __uint_as_float(v.z << 16);
    f[5] = __uint_as_float(v.z & 0xffff0000u);
    f[6] = __uint_as_float(v.w << 16);
    f[7] = __uint_as_float(v.w & 0xffff0000u);
}

__device__ inline unsigned f32_to_bf16(float x) {  // RTNE
    unsigned u = __float_as_uint(x);
    return (u + 0x7fffu + ((u >> 16) & 1u)) >> 16;
}

__device__ inline uint4 f32x8_to_bf16(const float* f) {
    uint4 v;
    v.x = f32_to_bf16(f[0]) | (f32_to_bf16(f[1]) << 16);
    v.y = f32_to_bf16(f[2]) | (f32_to_bf16(f[3]) << 16);
    v.z = f32_to_bf16(f[4]) | (f32_to_bf16(f[5]) << 16);
    v.w = f32_to_bf16(f[6]) | (f32_to_bf16(f[7]) << 16);
    return v;
}

// ------------------------------------------------ hist + per-edge rank
__global__ __launch_bounds__(256) void hist_rank_kernel(const int* __restrict__ dst,
                                                        int* __restrict__ cnt,
                                                        int* __restrict__ rank) {
    int i = blockIdx.x * blockDim.x + threadIdx.x;
    if (i < NE) rank[i] = atomicAdd(&cnt[dst[i]], 1);
}

// ------------------------------------------------ 3-kernel parallel scan
__global__ __launch_bounds__(256) void scan_block_kernel(const int* __restrict__ cnt,
                                                         int* __restrict__ row_ptr,
                                                         int* __restrict__ partial,
                                                         int n) {
    __shared__ int wsums[4];
    int i = blockIdx.x * 256 + threadIdx.x;
    int v = (i < n) ? cnt[i] : 0;
    const int lane = threadIdx.x & 63;
    const int wid = threadIdx.x >> 6;
    int incl = v;
    #pragma unroll
    for (int off = 1; off < 64; off <<= 1) {
        int t = __shfl_up(incl, off);
        if (lane >= off) incl += t;
    }
    if (lane == 63) wsums[wid] = incl;
    __syncthreads();
    int woff = 0;
    #pragma unroll
    for (int w = 0; w < 4; ++w)
        if (w < wid) woff += wsums[w];
    if (i < n) row_ptr[i] = woff + incl - v;
    if (threadIdx.x == 0)
        partial[blockIdx.x] = wsums[0] + wsums[1] + wsums[2] + wsums[3];
}

__global__ __launch_bounds__(256) void scan_partials_kernel(int* __restrict__ partial,
                                                            int* __restrict__ pexcl,
                                                            int* __restrict__ row_ptr,
                                                            int np) {
    __shared__ int wsums[4];
    int v = (threadIdx.x < np) ? partial[threadIdx.x] : 0;
    const int lane = threadIdx.x & 63;
    const int wid = threadIdx.x >> 6;
    int incl = v;
    #pragma unroll
    for (int off = 1; off < 64; off <<= 1) {
        int t = __shfl_up(incl, off);
        if (lane >= off) incl += t;
    }
    if (lane == 63) wsums[wid] = incl;
    __syncthreads();
    int woff = 0;
    #pragma unroll
    for (int w = 0; w < 4; ++w)
        if (w < wid) woff += wsums[w];
    if (threadIdx.x < np) pexcl[threadIdx.x] = woff + incl - v;
    if (threadIdx.x == 0) row_ptr[NN] = NE;
}

__global__ __launch_bounds__(256) void scan_add_kernel(int* __restrict__ row_ptr,
                                                       const int* __restrict__ pexcl,
                                                       int n) {
    int i = blockIdx.x * 256 + threadIdx.x;
    if (i < n) row_ptr[i] += pexcl[blockIdx.x];
}

// ------------------------------------------------ CSR fill (atomic-free, 4B rec)
__global__ __launch_bounds__(256) void fill_kernel(const int* __restrict__ src,
                                                   const int* __restrict__ dst,
                                                   const float* __restrict__ w,
                                                   const int* __restrict__ row_ptr,
                                                   const int* __restrict__ rank,
                                                   unsigned* __restrict__ er) {
    int i = blockIdx.x * blockDim.x + threadIdx.x;
    if (i < NE) {
        int p = row_ptr[dst[i]] + rank[i];
        er[p] = (f32_to_bf16(w[i]) << 16) | (unsigned)src[i];
    }
}

// ------------------------------------------------ weighted in-degree per node
__global__ __launch_bounds__(256) void degw_kernel(const int* __restrict__ row_ptr,
                                                   const unsigned* __restrict__ er,
                                                   float* __restrict__ degw) {
    int n = blockIdx.x * 256 + threadIdx.x;
    if (n < NN) {
        float s = 0.f;
        int end = row_ptr[n + 1];
        for (int e = row_ptr[n]; e < end; ++e)
            s += __uint_as_float(er[e] & 0xffff0000u);
        degw[n] = s;
    }
}

// ------------------------------------------------ W12T[n][k] = sum_j W1[k][j]*W2[j][n]
__global__ __launch_bounds__(256) void w12t_kernel(const float* __restrict__ W1,
                                                   const float* __restrict__ W2,
                                                   unsigned short* __restrict__ W12T) {
    int i = blockIdx.x * 256 + threadIdx.x;  // i = n*256 + k, n<64, k<256
    if (i < 64 * 256) {
        int n = i >> 8, k = i & 255;
        float s = 0.f;
        for (int j = 0; j < 128; ++j)
            s += W1[(size_t)k * 128 + j] * W2[(size_t)j * 64 + n];
        W12T[i] = (unsigned short)f32_to_bf16(s);
    }
}

// ------------------------------------------------ c[d] = sum_k b1[k]*W2[k][d]
__global__ __launch_bounds__(64) void cvec_kernel(const float* __restrict__ b1,
                                                  const float* __restrict__ W2,
                                                  float* __restrict__ c) {
    int d = threadIdx.x;
    float s = 0.f;
    for (int k = 0; k < 128; ++k) s += b1[k] * W2[(size_t)k * 64 + d];
    c[d] = s;
}

// ------------------------------------------------ MFMA bf16 GEMM (A fp32)
// C[M,N] bf16 = A[M,K] fp32 @ BT[N,K] bf16.  BM=64, 256 thr = 4 waves.
template <int N, int K>
__global__ __launch_bounds__(256) void gemm_mfma_kernel(
    const float* __restrict__ A, const unsigned short* __restrict__ BT,
    unsigned short* __restrict__ C, int M) {
    constexpr int NT = N / 16;
    constexpr int KS = K / 32;
    __shared__ unsigned short As[64][40];
    __shared__ unsigned short Bs[N][40];

    const int tid = threadIdx.x;
    const int wave = tid >> 6;
    const int lane = tid & 63;
    const int lm = lane & 15;
    const int lq = lane >> 4;
    const int row0 = blockIdx.x * 64;
    const int m0 = wave * 16;

    f32x4 acc[NT] = {};

    for (int ks = 0; ks < KS; ++ks) {
        const int k0 = ks * 32;
        {
            int m = tid >> 2, kc = (tid & 3) * 8;
            int gm = row0 + m;
            if (gm >= M) gm = M - 1;
            float4 v0 = *(const float4*)(A + (size_t)gm * K + k0 + kc);
            float4 v1 = *(const float4*)(A + (size_t)gm * K + k0 + kc + 4);
            float f[8] = {v0.x, v0.y, v0.z, v0.w, v1.x, v1.y, v1.z, v1.w};
            *(uint4*)&As[m][kc] = f32x8_to_bf16(f);
        }
        #pragma unroll
        for (int c = tid; c < N * 4; c += 256) {
            int n = c >> 2, kc = (c & 3) * 8;
            *(uint4*)&Bs[n][kc] = *(const uint4*)(BT + (size_t)n * K + k0 + kc);
        }
        __syncthreads();
        bf16x8 a = *(const bf16x8*)&As[m0 + lm][lq * 8];
        #pragma unroll
        for (int t = 0; t < NT; ++t) {
            bf16x8 b = *(const bf16x8*)&Bs[t * 16 + lm][lq * 8];
            acc[t] = __builtin_amdgcn_mfma_f32_16x16x32_bf16(a, b, acc[t], 0, 0, 0);
        }
        __syncthreads();
    }
    #pragma unroll
    for (int t = 0; t < NT; ++t) {
        #pragma unroll
        for (int r = 0; r < 4; ++r) {
            int gm = row0 + m0 + lq * 4 + r;
            if (gm < M)
                C[(size_t)gm * N + t * 16 + lm] =
                    (unsigned short)f32_to_bf16(acc[t][r]);
        }
    }
}

// ------------------------------------------------ propagation D=64 (bf16, 4B rec)
// rec = bf16(w)<<16 | src (src < 65536 since NN=50000).
// MODE 0: out = acc                         (plain, conv1-fused)
// MODE 2: out = acc + degw[n]*c[d] + b2[d]  (conv2 epilogue)
// MODE 1: out = 0.9*acc + 0.1*h[n][d]       (APPNP step)
template <int MODE, bool OUT_BF16>
__global__ __launch_bounds__(256, 4) void prop_kernel(
    const int* __restrict__ row_ptr, const unsigned* __restrict__ er,
    const unsigned short* __restrict__ x, const float* __restrict__ cvec,
    const float* __restrict__ b2, const float* __restrict__ degw,
    const unsigned short* __restrict__ hbf, void* __restrict__ outv) {
    constexpr int D = 64;
    const int local = threadIdx.x >> 3;     // node within block (32/block)
    const int lane = threadIdx.x & 7;       // 8 threads/node, 16B each
    const int n = blockIdx.x * 32 + local;
    if (n >= NN) return;

    int e = row_ptr[n];
    const int end = row_ptr[n + 1];

    float acc[8] = {};
    float f[8];
    for (; e + 3 < end; e += 4) {
        unsigned r0 = er[e], r1 = er[e + 1], r2 = er[e + 2], r3 = er[e + 3];
        uint4 u0 = *(const uint4*)(x + (size_t)(r0 & 0xffffu) * D + lane * 8);
        uint4 u1 = *(const uint4*)(x + (size_t)(r1 & 0xffffu) * D + lane * 8);
        uint4 u2 = *(const uint4*)(x + (size_t)(r2 & 0xffffu) * D + lane * 8);
        uint4 u3 = *(const uint4*)(x + (size_t)(r3 & 0xffffu) * D + lane * 8);
        float w0 = __uint_as_float(r0 & 0xffff0000u);
        float w1 = __uint_as_float(r1 & 0xffff0000u);
        float w2 = __uint_as_float(r2 & 0xffff0000u);
        float w3 = __uint_as_float(r3 & 0xffff0000u);
        bf16x8_to_f32(u0, f);
        #pragma unroll
        for (int j = 0; j < 8; ++j) acc[j] += w0 * f[j];
        bf16x8_to_f32(u1, f);
        #pragma unroll
        for (int j = 0; j < 8; ++j) acc[j] += w1 * f[j];
        bf16x8_to_f32(u2, f);
        #pragma unroll
        for (int j = 0; j < 8; ++j) acc[j] += w2 * f[j];
        bf16x8_to_f32(u3, f);
        #pragma unroll
        for (int j = 0; j < 8; ++j) acc[j] += w3 * f[j];
    }
    for (; e < end; ++e) {
        unsigned r0 = er[e];
        uint4 u0 = *(const uint4*)(x + (size_t)(r0 & 0xffffu) * D + lane * 8);
        float w0 = __uint_as_float(r0 & 0xffff0000u);
        bf16x8_to_f32(u0, f);
        #pragma unroll
        for (int j = 0; j < 8; ++j) acc[j] += w0 * f[j];
    }

    float r[8];
    if (MODE == 0) {
        #pragma unroll
        for (int j = 0; j < 8; ++j) r[j] = acc[j];
    } else if (MODE == 2) {
        float dw = degw[n];
        #pragma unroll
        for (int j = 0; j < 8; ++j)
            r[j] = acc[j] + dw * cvec[lane * 8 + j] + b2[lane * 8 + j];
    } else {
        uint4 uh = *(const uint4*)(hbf + (size_t)n * D + lane * 8);
        float fh[8];
        bf16x8_to_f32(uh, fh);
        #pragma unroll
        for (int j = 0; j < 8; ++j) r[j] = 0.9f * acc[j] + 0.1f * fh[j];
    }

    if (OUT_BF16) {
        *(uint4*)((unsigned short*)outv + (size_t)n * D + lane * 8) =
            f32x8_to_bf16(r);
    } else {
        float* o = (float*)outv + (size_t)n * D + lane * 8;
        *(float4*)(o + 0) = make_float4(r[0], r[1], r[2], r[3]);
        *(float4*)(o + 4) = make_float4(r[4], r[5], r[6], r[7]);
    }
}

__global__ void write_scalar_kernel(float* p, float v) { *p = v; }

// ------------------------------------------------ launch
extern "C" void kernel_launch(void* const* d_in, const int* in_sizes, int n_in,
                              void* d_out, int out_size, void* d_ws, size_t ws_size,
                              hipStream_t stream) {
    const float* features = (const float*)d_in[0];
    const int* edge_index = (const int*)d_in[1];
    const float* edge_w = (const float*)d_in[2];
    const float* W1 = (const float*)d_in[3];
    const float* b1 = (const float*)d_in[4];
    const float* W2 = (const float*)d_in[5];
    const float* b2 = (const float*)d_in[6];
    const int* src = edge_index;        // edge_index[0]
    const int* dst = edge_index + NE;   // edge_index[1]

    char* ws = (char*)d_ws;
    auto carve = [&](size_t bytes) {
        char* p = ws;
        ws += (bytes + 255) & ~(size_t)255;
        return p;
    };
    int* cnt = (int*)carve((size_t)NN * 4);
    int* rank = (int*)carve((size_t)NE * 4);
    int* row_ptr = (int*)carve((size_t)(NN + 1) * 4);
    int* partial = (int*)carve((size_t)SCAN_NB * 4);
    int* pexcl = (int*)carve((size_t)SCAN_NB * 4);
    unsigned* erec = (unsigned*)carve((size_t)NE * 4);
    float* degw = (float*)carve((size_t)NN * 4);
    float* cvec = (float*)carve((size_t)64 * 4);
    unsigned short* W12T = (unsigned short*)carve((size_t)64 * 256 * 2);
    unsigned short* z_bf = (unsigned short*)carve((size_t)NN * 64 * 2);
    unsigned short* p1_bf = (unsigned short*)carve((size_t)NN * 64 * 2);
    unsigned short* h_bf = (unsigned short*)carve((size_t)NN * 64 * 2);
    unsigned short* xb0 = (unsigned short*)carve((size_t)NN * 64 * 2);
    unsigned short* xb1 = (unsigned short*)carve((size_t)NN * 64 * 2);

    const int EB = (NE + 255) / 256;
    const int PB = (NN + 31) / 32;   // prop blocks (32 nodes each)

    // ---- CSR build (by destination) ----
    hipMemsetAsync(cnt, 0, (size_t)NN * 4, stream);
    hist_rank_kernel<<<EB, 256, 0, stream>>>(dst, cnt, rank);
    scan_block_kernel<<<SCAN_NB, 256, 0, stream>>>(cnt, row_ptr, partial, NN);
    scan_partials_kernel<<<1, 256, 0, stream>>>(partial, pexcl, row_ptr, SCAN_NB);
    scan_add_kernel<<<SCAN_NB, 256, 0, stream>>>(row_ptr, pexcl, NN);
    fill_kernel<<<EB, 256, 0, stream>>>(src, dst, edge_w, row_ptr, rank, erec);
    degw_kernel<<<(NN + 255) / 256, 256, 0, stream>>>(row_ptr, erec, degw);

    // ---- fused weights: W12T = (W1@W2)^T bf16, cvec = b1@W2 ----
    w12t_kernel<<<64, 256, 0, stream>>>(W1, W2, W12T);
    cvec_kernel<<<1, 64, 0, stream>>>(b1, W2, cvec);

    // ---- z = F @ W12  [NN,64] bf16 ----
    gemm_mfma_kernel<64, 256>
        <<<(NN + 63) / 64, 256, 0, stream>>>(features, W12T, z_bf, NN);

    // ---- p1 = prop(z);  h = prop(p1) + degw*c + b2 ----
    prop_kernel<0, true><<<PB, 256, 0, stream>>>(row_ptr, erec, z_bf, nullptr,
                                                 nullptr, nullptr, nullptr, p1_bf);
    prop_kernel<2, true><<<PB, 256, 0, stream>>>(row_ptr, erec, p1_bf, cvec, b2,
                                                 degw, nullptr, h_bf);

    // ---- APPNP: 10 steps of x = 0.9*prop(x) + 0.1*h ----
    const unsigned short* x_cur = h_bf;
    for (int k = 0; k < 9; ++k) {
        unsigned short* out = (k & 1) ? xb1 : xb0;
        prop_kernel<1, true><<<PB, 256, 0, stream>>>(row_ptr, erec, x_cur, nullptr,
                                                     nullptr, nullptr, h_bf, out);
        x_cur = out;
    }
    prop_kernel<1, false><<<PB, 256, 0, stream>>>(row_ptr, erec, x_cur, nullptr,
                                                  nullptr, nullptr, h_bf,
                                                  (float*)d_out);

    // ---- second tuple element: the Python int 10 ----
    if (out_size > NN * 64) {
        write_scalar_kernel<<<1, 1, 0, stream>>>((float*)d_out + (size_t)NN * 64,
                                                 10.0f);
    }
}